// Round 10
// baseline (5082.640 us; speedup 1.0000x reference)
//
#include <hip/hip_runtime.h>
#include <hip/hip_bf16.h>
#include <math.h>

// ---------------- problem dims (fixed by setup_inputs) ----------------
constexpr int B  = 8,  V = 64, E = 512, NS = 32;
constexpr int L  = 4,  H = 8,  D = 64,  M  = 1024, R = 128;
constexpr int HD = H * D;            // 512
constexpr int ROWS  = B * V;         // 512 distinct transformer rows
constexpr int SROWS = ROWS * NS;     // 16384 sample rows
constexpr int KVN = 4096;            // kv output columns (keys 2048 | vals 2048)
constexpr int NBLK = 512;            // persistent grid: 2 blocks/CU x 256 CUs

typedef _Float16 half8 __attribute__((ext_vector_type(8)));
typedef float floatx4 __attribute__((ext_vector_type(4)));

// ---------------- threefry2x32-20 (JAX-compatible, partitionable) ----------
struct TF2 { unsigned a, b; };
__host__ __device__ constexpr unsigned rotl32(unsigned x, int d) {
  return (x << d) | (x >> (32 - d));
}
__host__ __device__ constexpr TF2 threefry(unsigned k0, unsigned k1,
                                           unsigned x0, unsigned x1) {
  unsigned ks2 = k0 ^ k1 ^ 0x1BD11BDAu;
  x0 += k0; x1 += k1;
  const int ra[4] = {13, 15, 26, 6};
  const int rb[4] = {17, 29, 16, 24};
  for (int i = 0; i < 4; i++) { x0 += x1; x1 = rotl32(x1, ra[i]); x1 ^= x0; }
  x0 += k1;  x1 += ks2 + 1u;
  for (int i = 0; i < 4; i++) { x0 += x1; x1 = rotl32(x1, rb[i]); x1 ^= x0; }
  x0 += ks2; x1 += k0 + 2u;
  for (int i = 0; i < 4; i++) { x0 += x1; x1 = rotl32(x1, ra[i]); x1 ^= x0; }
  x0 += k0;  x1 += k1 + 3u;
  for (int i = 0; i < 4; i++) { x0 += x1; x1 = rotl32(x1, rb[i]); x1 ^= x0; }
  x0 += k1;  x1 += ks2 + 4u;
  for (int i = 0; i < 4; i++) { x0 += x1; x1 = rotl32(x1, ra[i]); x1 ^= x0; }
  x0 += ks2; x1 += k0 + 5u;
  return {x0, x1};
}
__device__ __forceinline__ unsigned tf_bits32(unsigned k0, unsigned k1,
                                              unsigned j) {
  TF2 r = threefry(k0, k1, 0u, j);
  return r.a ^ r.b;
}

__device__ __forceinline__ double waveReduceAdd64(double v) {
#pragma unroll
  for (int m = 32; m; m >>= 1) v += __shfl_xor(v, m, 64);
  return v;
}

__device__ __forceinline__ void split16(float v, _Float16& h, _Float16& l) {
  h = (_Float16)v;
  l = (_Float16)((v - (float)h) * 2048.0f);
}

// ---------------- args ----------------
struct MA {
  unsigned* cnt; unsigned* gen;
  const float *flow, *Wsh, *bsh, *Wk, *bk, *Wv, *bv;
  const float *ln1g, *ln1b, *W1, *b1, *W2, *b2, *W3, *b3, *ln2g, *ln2b;
  const float *Wd, *bd;
  float *kv, *att, *logits, *kvb, *P, *out;
  _Float16 *flow_h, *flow_l, *BKV_h, *BKV_l;
  _Float16 *W1_h, *W1_l, *W2_h, *W2_l, *W3_h, *W3_l, *Wd_h, *Wd_l;
  _Float16 *att_h, *att_l, *h1_h, *h1_l, *h2_h, *h2_l;
};

// ---------------- device-scope grid barrier (all NBLK co-resident) ---------
__device__ __forceinline__ void grid_sync(unsigned* cnt, unsigned* gen) {
  __threadfence();          // agent-scope release of this thread's writes
  __syncthreads();
  if (threadIdx.x == 0) {
    unsigned g = __hip_atomic_load(gen, __ATOMIC_RELAXED,
                                   __HIP_MEMORY_SCOPE_AGENT);
    unsigned a = __hip_atomic_fetch_add(cnt, 1u, __ATOMIC_ACQ_REL,
                                        __HIP_MEMORY_SCOPE_AGENT);
    if (a == (unsigned)NBLK - 1u) {
      __hip_atomic_store(cnt, 0u, __ATOMIC_RELAXED, __HIP_MEMORY_SCOPE_AGENT);
      __hip_atomic_fetch_add(gen, 1u, __ATOMIC_RELEASE,
                             __HIP_MEMORY_SCOPE_AGENT);
    } else {
      while (__hip_atomic_load(gen, __ATOMIC_ACQUIRE,
                               __HIP_MEMORY_SCOPE_AGENT) == g)
        __builtin_amdgcn_s_sleep(2);
    }
  }
  __syncthreads();
  __threadfence();          // agent-scope acquire for subsequent reads
}

// ---------------- phase bodies (all bit-identical to R9 kernels) -----------
__device__ __forceinline__ void dev_prep(const MA& a, int blk) {
  const int t = threadIdx.x;
  if (blk < 256) {
    const int base = (blk * 256 + t) * 4;
    float4 v = *(const float4*)&a.flow[base];
    float x[4] = {v.x, v.y, v.z, v.w};
#pragma unroll
    for (int j = 0; j < 4; j++) {
      _Float16 h, l;
      split16(x[j], h, l);
      a.flow_h[base + j] = h;
      a.flow_l[base + j] = l;
    }
  } else {
    const int idx = (blk - 256) * 256 + t;
    if (idx < KVN + HD) {
      float bb = (idx < 2048) ? a.bk[idx]
               : (idx < 4096) ? a.bv[idx - 2048]
                              : a.bsh[idx - 4096];
      a.kvb[idx] = bb;
    }
  }
}

// 0 Wsh(512,512) 1 Wk x32 2 Wv x32 3 W1 x4 4 W2 x4 5 W3 x4 6 Wd
__device__ __forceinline__ void dev_wsplit(const MA& a, int bid) {
  __shared__ float tile[64][65];
  const int WS_OFF[8] = {0, 64, 320, 576, 1088, 2112, 2624, 2640};
  const int WS_K[7] = {512, 512, 512, 512, 1024, 1024, 512};
  const int WS_N[7] = {512, 64, 64, 1024, 1024, 512, 128};
  const float* srcs[7] = {a.Wsh, a.Wk, a.Wv, a.W1, a.W2, a.W3, a.Wd};
  _Float16* dhs[7] = {a.BKV_h + 4096 * 512, a.BKV_h, a.BKV_h + 2048 * 512,
                      a.W1_h, a.W2_h, a.W3_h, a.Wd_h};
  _Float16* dls[7] = {a.BKV_l + 4096 * 512, a.BKV_l, a.BKV_l + 2048 * 512,
                      a.W1_l, a.W2_l, a.W3_l, a.Wd_l};
  int mi = 0;
  while (bid >= WS_OFF[mi + 1]) mi++;
  int tt = bid - WS_OFF[mi];
  const int K = WS_K[mi], N = WS_N[mi];
  const int ktiles = K >> 6;
  const int per = ktiles * (N >> 6);
  const int z = tt / per;
  const int rem = tt - z * per;
  const int k0 = (rem % ktiles) * 64, n0 = (rem / ktiles) * 64;
  const size_t moff = (size_t)z * K * N;
  const float* src = srcs[mi] + moff;
  _Float16* dh = dhs[mi] + moff;
  _Float16* dl = dls[mi] + moff;
  const int t = threadIdx.x;
#pragma unroll
  for (int i = 0; i < 16; i++) {
    int idx = i * 256 + t, r = idx >> 6, c = idx & 63;
    tile[r][c] = src[(size_t)(k0 + r) * N + n0 + c];
  }
  __syncthreads();
#pragma unroll
  for (int i = 0; i < 16; i++) {
    int idx = i * 256 + t, n = idx >> 6, k = idx & 63;
    float v = tile[k][n];
    _Float16 h, l;
    split16(v, h, l);
    dh[(size_t)(n0 + n) * K + k0 + k] = h;
    dl[(size_t)(n0 + n) * K + k0 + k] = l;
  }
  __syncthreads();  // tile reused by next virtual block
}

// 64x64 split-K MFMA GEMM: async gll staging, fragment-order LDS (verified).
__device__ __forceinline__ void dev_gemm(
    const _Float16* __restrict__ Ah, const _Float16* __restrict__ Al,
    const _Float16* __restrict__ Bh, const _Float16* __restrict__ Bl,
    float* __restrict__ P, int K, int kchunk, int Ndim, int nx, int vb) {
  __shared__ __align__(16) _Float16 lds[2 * 8192];
  const int t = threadIdx.x, lane = t & 63, wave = t >> 6;
  const int quad = lane >> 4, l15 = lane & 15;
  const int per = nx * 8;
  const int z = vb / per, rem = vb - z * per;
  const int n0 = (rem % nx) * 64, m0 = (rem / nx) * 64;
  const int kbase = z * kchunk;
  const int KT = kchunk >> 5;
  const _Float16* srcs[4] = {Ah + (size_t)m0 * K, Al + (size_t)m0 * K,
                             Bh + (size_t)n0 * K, Bl + (size_t)n0 * K};
  const _Float16* gsrc = srcs[wave] + (size_t)l15 * K + quad * 8 + kbase;
  auto stage = [&](int buf, int kt) {
    _Float16* base = &lds[buf * 8192 + wave * 2048];
    const int koff = kt * 32;
#pragma unroll
    for (int f = 0; f < 4; f++)
      __builtin_amdgcn_global_load_lds(gsrc + (size_t)(f * 16) * K + koff,
                                       base + f * 512, 16, 0, 0);
  };
  const int wm = wave >> 1, wn = wave & 1;
  floatx4 hh[2][2], mid[2][2];
#pragma unroll
  for (int i = 0; i < 2; i++)
#pragma unroll
    for (int j = 0; j < 2; j++) {
      hh[i][j] = (floatx4){0.f, 0.f, 0.f, 0.f};
      mid[i][j] = (floatx4){0.f, 0.f, 0.f, 0.f};
    }
  stage(0, 0);
  __syncthreads();
  for (int kt = 0; kt < KT; kt++) {
    if (kt + 1 < KT) stage((kt + 1) & 1, kt + 1);
    const int b = (kt & 1) * 8192;
    half8 a_h[2], a_l[2], b_h[2], b_l[2];
#pragma unroll
    for (int i = 0; i < 2; i++) {
      const int af = (wm * 2 + i) * 512 + lane * 8;
      const int bf = (wn * 2 + i) * 512 + lane * 8;
      a_h[i] = *(const half8*)&lds[b + af];
      a_l[i] = *(const half8*)&lds[b + 2048 + af];
      b_h[i] = *(const half8*)&lds[b + 4096 + bf];
      b_l[i] = *(const half8*)&lds[b + 6144 + bf];
    }
#pragma unroll
    for (int i = 0; i < 2; i++)
#pragma unroll
      for (int j = 0; j < 2; j++) {
        hh[i][j] = __builtin_amdgcn_mfma_f32_16x16x32_f16(a_h[i], b_h[j],
                                                          hh[i][j], 0, 0, 0);
        mid[i][j] = __builtin_amdgcn_mfma_f32_16x16x32_f16(a_h[i], b_l[j],
                                                           mid[i][j], 0, 0, 0);
        mid[i][j] = __builtin_amdgcn_mfma_f32_16x16x32_f16(a_l[i], b_h[j],
                                                           mid[i][j], 0, 0, 0);
      }
    __syncthreads();
  }
  float* Pz = P + (size_t)z * ROWS * Ndim;
#pragma unroll
  for (int i = 0; i < 2; i++)
#pragma unroll
    for (int j = 0; j < 2; j++)
#pragma unroll
      for (int r = 0; r < 4; r++) {
        float v = hh[i][j][r] + mid[i][j][r] * (1.0f / 2048.0f);
        const int m = m0 + (wm * 2 + i) * 16 + quad * 4 + r;
        const int n = n0 + (wn * 2 + j) * 16 + l15;
        Pz[(size_t)m * Ndim + n] = v;
      }
}

__device__ __forceinline__ void dev_epi_kv(const MA& a, int vb) {
  const int n = (vb % 18) * 256 + threadIdx.x;
  const int m = vb / 18;
  const size_t MN = (size_t)ROWS * 4608;
  const size_t id = (size_t)m * 4608 + n;
  float v = a.P[id] + a.P[MN + id] + a.kvb[n];
  if (n < KVN) a.kv[(size_t)m * KVN + n] = v;
  else a.att[(size_t)m * HD + (n - KVN)] = v;
}

__device__ __forceinline__ void dev_epi_h(
    const float* __restrict__ P, const float* __restrict__ bias,
    _Float16* __restrict__ Oh, _Float16* __restrict__ Ol, int Ndim, int kz,
    int relu, int vb) {
  const int nchunks = Ndim >> 8;
  const int n = (vb % nchunks) * 256 + threadIdx.x;
  const int m = vb / nchunks;
  const size_t MN = (size_t)ROWS * Ndim;
  const size_t id = (size_t)m * Ndim + n;
  float v = 0.0f;
  for (int z = 0; z < kz; z++) v += P[z * MN + id];
  v += bias[n];
  if (relu) v = fmaxf(v, 0.0f);
  _Float16 h, l;
  split16(v, h, l);
  Oh[id] = h;
  Ol[id] = l;
}

__device__ __forceinline__ void dev_epi_f(const MA& a, int vb, int kz) {
  const int n = threadIdx.x;
  if (n >= R) return;
  const int m = vb;
  const size_t MN = (size_t)ROWS * R;
  const size_t id = (size_t)m * R + n;
  float v = 0.0f;
  for (int z = 0; z < kz; z++) v += a.P[z * MN + id];
  a.logits[id] = v + a.bd[n];
}

__device__ __forceinline__ void dev_epi_ln(const MA& a, int l, int kz,
                                           int row) {
  __shared__ double rb[8];
  const float* b3 = a.b3 + l * HD;
  const float* g = a.ln2g + l * HD;
  const float* bb = a.ln2b + l * HD;
  const int t = threadIdx.x;
  const size_t MN = (size_t)ROWS * HD;
  const size_t id0 = (size_t)row * HD + t;
  float h0 = 0.0f, h1s = 0.0f;
  for (int z = 0; z < kz; z++) {
    h0 += a.P[z * MN + id0];
    h1s += a.P[z * MN + id0 + 256];
  }
  h0 += b3[t];
  h1s += b3[t + 256];
  float x0 = a.att[id0] + h0;
  float x1 = a.att[id0 + 256] + h1s;
  double s1 = (double)x0 + (double)x1;
  double s2 = (double)x0 * (double)x0 + (double)x1 * (double)x1;
  s1 = waveReduceAdd64(s1);
  s2 = waveReduceAdd64(s2);
  const int wid = t >> 6, lane = t & 63;
  if (lane == 0) { rb[wid] = s1; rb[4 + wid] = s2; }
  __syncthreads();
  double S1 = rb[0] + rb[1] + rb[2] + rb[3];
  double S2 = rb[4] + rb[5] + rb[6] + rb[7];
  double mean = S1 / (double)HD;
  double var  = S2 / (double)HD - mean * mean;
  double inv  = 1.0 / sqrt(var + (double)1e-5f);
  float y0 = (float)(((double)x0 - mean) * inv * (double)g[t] + (double)bb[t]);
  float y1 = (float)(((double)x1 - mean) * inv * (double)g[t + 256] +
                     (double)bb[t + 256]);
  a.att[id0] = y0;
  a.att[id0 + 256] = y1;
  _Float16 hh0, ll0, hh1, ll1;
  split16(y0, hh0, ll0);
  split16(y1, hh1, ll1);
  a.att_h[id0] = hh0;
  a.att_l[id0] = ll0;
  a.att_h[id0 + 256] = hh1;
  a.att_l[id0 + 256] = ll1;
  __syncthreads();  // rb reused by next virtual block
}

__device__ __forceinline__ void dev_attn(const MA& a, int l, int row) {
  __shared__ float q[HD];
  __shared__ float sp[HD];
  __shared__ double rb[8];
  const float* g = a.ln1g + l * HD;
  const float* bb = a.ln1b + l * HD;
  const int t = threadIdx.x;
  const int b_ = row >> 6;
  q[t]       = a.att[row * HD + t];
  q[t + 256] = a.att[row * HD + 256 + t];
  __syncthreads();
#pragma unroll
  for (int rep = 0; rep < 2; rep++) {
    int idx = t + rep * 256;
    int h = idx >> 6, w = idx & 63;
    const float* kp = a.kv + (size_t)(b_ * 64 + w) * KVN + (l * 8 + h) * 64;
    const float* qp = q + h * D;
    double s = 0.0;
#pragma unroll 8
    for (int d = 0; d < 64; d++) s += (double)qp[d] * (double)kp[d];
    sp[idx] = (float)s * 0.125f;
  }
  __syncthreads();
  {
    int h = t >> 5, w0 = t & 31;
    float s0 = sp[h * 64 + w0], s1 = sp[h * 64 + w0 + 32];
    float mx = fmaxf(s0, s1);
#pragma unroll
    for (int m = 16; m; m >>= 1) mx = fmaxf(mx, __shfl_xor(mx, m, 32));
    float e0 = expf(s0 - mx), e1 = expf(s1 - mx);
    double sm = (double)e0 + (double)e1;
#pragma unroll
    for (int m = 16; m; m >>= 1) sm += __shfl_xor(sm, m, 32);
    sp[h * 64 + w0]      = (float)((double)e0 / sm);
    sp[h * 64 + w0 + 32] = (float)((double)e1 / sm);
  }
  __syncthreads();
  float x[2];
#pragma unroll
  for (int rep = 0; rep < 2; rep++) {
    int idx = t + rep * 256;
    int h = idx >> 6, d = idx & 63;
    const float* vp =
        a.kv + (size_t)(b_ * 64) * KVN + 2048 + (l * 8 + h) * 64 + d;
    const float* pp = sp + h * 64;
    double acc = 0.0;
#pragma unroll 8
    for (int w = 0; w < 64; w++)
      acc += (double)pp[w] * (double)vp[(size_t)w * KVN];
    x[rep] = q[idx] + (float)acc;
  }
  double s1 = (double)x[0] + (double)x[1];
  double s2 = (double)x[0] * (double)x[0] + (double)x[1] * (double)x[1];
  s1 = waveReduceAdd64(s1);
  s2 = waveReduceAdd64(s2);
  const int wid = t >> 6, lane = t & 63;
  if (lane == 0) { rb[wid] = s1; rb[4 + wid] = s2; }
  __syncthreads();
  double S1 = rb[0] + rb[1] + rb[2] + rb[3];
  double S2 = rb[4] + rb[5] + rb[6] + rb[7];
  double mean = S1 / (double)HD;
  double var  = S2 / (double)HD - mean * mean;
  double inv  = 1.0 / sqrt(var + (double)1e-5f);
  float y0 =
      (float)(((double)x[0] - mean) * inv * (double)g[t] + (double)bb[t]);
  float y1 = (float)(((double)x[1] - mean) * inv * (double)g[t + 256] +
                     (double)bb[t + 256]);
  a.att[row * HD + t] = y0;
  a.att[row * HD + 256 + t] = y1;
  _Float16 h0, l0, h1v, l1v;
  split16(y0, h0, l0);
  split16(y1, h1v, l1v);
  a.att_h[row * HD + t] = h0;
  a.att_l[row * HD + t] = l0;
  a.att_h[row * HD + 256 + t] = h1v;
  a.att_l[row * HD + 256 + t] = l1v;
  __syncthreads();  // q/sp/rb reused by next virtual block
}

__device__ __forceinline__ void dev_sample(const MA& a, int vb) {
  constexpr TF2 KC = threefry(0u, 1u, 0u, 0u);  // fold_in(key(1), 0)
  constexpr TF2 KU = threefry(0u, 1u, 0u, 1u);  // fold_in(key(1), 1)
  const int lane = threadIdx.x & 63;
  const int wid = threadIdx.x >> 6;
  const int row = vb * 4 + wid;
  const float* lrow = a.logits + (row >> 5) * R;
  float bvv = -1e30f;
  int bi = 0;
#pragma unroll
  for (int rep = 0; rep < 2; rep++) {
    int r = lane + rep * 64;
    unsigned j = (unsigned)row * (unsigned)R + (unsigned)r;
    unsigned bits = tf_bits32(KC.a, KC.b, j);
    float f = __uint_as_float((bits >> 9) | 0x3f800000u) - 1.0f;
    float u = fmaxf(f, 1.17549435e-38f);
    float gv = -logf(-logf(u));
    float v = lrow[r] + gv;
    if (v > bvv) { bvv = v; bi = r; }
  }
#pragma unroll
  for (int m = 32; m; m >>= 1) {
    float ov = __shfl_xor(bvv, m, 64);
    int oi = __shfl_xor(bi, m, 64);
    if (ov > bvv || (ov == bvv && oi < bi)) { bvv = ov; bi = oi; }
  }
  if (lane == 0) {
    unsigned ub = tf_bits32(KU.a, KU.b, (unsigned)row);
    float u = __uint_as_float((ub >> 9) | 0x3f800000u) - 1.0f;
    a.out[row] = ((float)bi + u) * (1.0f / 128.0f);
  }
}

// ---------------- the mega kernel: whole pipeline, 33 grid barriers --------
__global__ __launch_bounds__(256, 2) void mega(MA a) {
  const int nb = (int)gridDim.x;
  // P0: prep (275) + weight transpose/split (2640)
  for (int vb = blockIdx.x; vb < 2915; vb += nb) {
    if (vb < 275) dev_prep(a, vb);
    else dev_wsplit(a, vb - 275);
  }
  grid_sync(a.cnt, a.gen);
  // P1: fused keys|vals|shift GEMM [512 x 4608 x 512], kz=2
  for (int vb = blockIdx.x; vb < 72 * 8 * 2; vb += nb)
    dev_gemm(a.flow_h, a.flow_l, a.BKV_h, a.BKV_l, a.P, 512, 256, 4608, 72,
             vb);
  grid_sync(a.cnt, a.gen);
  // P2: kv epilogue
  for (int vb = blockIdx.x; vb < 18 * ROWS; vb += nb) dev_epi_kv(a, vb);
  grid_sync(a.cnt, a.gen);
  // transformer layers
  for (int l = 0; l < L; l++) {
    for (int vb = blockIdx.x; vb < ROWS; vb += nb) dev_attn(a, l, vb);
    grid_sync(a.cnt, a.gen);
    for (int vb = blockIdx.x; vb < 16 * 8 * 4; vb += nb)
      dev_gemm(a.att_h, a.att_l, a.W1_h + (size_t)l * 524288,
               a.W1_l + (size_t)l * 524288, a.P, 512, 128, M, 16, vb);
    grid_sync(a.cnt, a.gen);
    for (int vb = blockIdx.x; vb < 4 * ROWS; vb += nb)
      dev_epi_h(a.P, a.b1 + l * M, a.h1_h, a.h1_l, M, 4, 1, vb);
    grid_sync(a.cnt, a.gen);
    for (int vb = blockIdx.x; vb < 16 * 8 * 8; vb += nb)
      dev_gemm(a.h1_h, a.h1_l, a.W2_h + (size_t)l * 1048576,
               a.W2_l + (size_t)l * 1048576, a.P, 1024, 128, M, 16, vb);
    grid_sync(a.cnt, a.gen);
    for (int vb = blockIdx.x; vb < 4 * ROWS; vb += nb)
      dev_epi_h(a.P, a.b2 + l * M, a.h2_h, a.h2_l, M, 8, 1, vb);
    grid_sync(a.cnt, a.gen);
    for (int vb = blockIdx.x; vb < 8 * 8 * 8; vb += nb)
      dev_gemm(a.h2_h, a.h2_l, a.W3_h + (size_t)l * 524288,
               a.W3_l + (size_t)l * 524288, a.P, 1024, 128, HD, 8, vb);
    grid_sync(a.cnt, a.gen);
    for (int vb = blockIdx.x; vb < ROWS; vb += nb) dev_epi_ln(a, l, 8, vb);
    grid_sync(a.cnt, a.gen);
  }
  // distribution head
  for (int vb = blockIdx.x; vb < 2 * 8 * 4; vb += nb)
    dev_gemm(a.att_h, a.att_l, a.Wd_h, a.Wd_l, a.P, 512, 128, R, 2, vb);
  grid_sync(a.cnt, a.gen);
  for (int vb = blockIdx.x; vb < ROWS; vb += nb) dev_epi_f(a, vb, 4);
  grid_sync(a.cnt, a.gen);
  // sampling (bit-exact threefry gumbel-argmax)
  for (int vb = blockIdx.x; vb < SROWS / 4; vb += nb) dev_sample(a, vb);
}

// ---------------- launcher ----------------
extern "C" void kernel_launch(void* const* d_in, const int* in_sizes, int n_in,
                              void* d_out, int out_size, void* d_ws,
                              size_t ws_size, hipStream_t stream) {
  (void)in_sizes; (void)n_in; (void)out_size; (void)ws_size;
  MA a;
  a.flow = (const float*)d_in[0];
  a.Wsh  = (const float*)d_in[1];
  a.bsh  = (const float*)d_in[2];
  a.Wk   = (const float*)d_in[3];
  a.bk   = (const float*)d_in[4];
  a.Wv   = (const float*)d_in[5];
  a.bv   = (const float*)d_in[6];
  a.ln1g = (const float*)d_in[7];
  a.ln1b = (const float*)d_in[8];
  a.W1   = (const float*)d_in[9];
  a.b1   = (const float*)d_in[10];
  a.W2   = (const float*)d_in[11];
  a.b2   = (const float*)d_in[12];
  a.W3   = (const float*)d_in[13];
  a.b3   = (const float*)d_in[14];
  a.ln2g = (const float*)d_in[15];
  a.ln2b = (const float*)d_in[16];
  a.Wd   = (const float*)d_in[17];
  a.bd   = (const float*)d_in[18];
  a.out  = (float*)d_out;

  // ---- workspace: [barrier 128B][f32 region][fp16 region] ----
  a.cnt = (unsigned*)d_ws;
  a.gen = a.cnt + 1;
  float* ws = (float*)((char*)d_ws + 128);
  a.kv     = ws;                          // 512*4096
  a.att    = a.kv + ROWS * KVN;           // 262,144
  a.logits = a.att + ROWS * HD;           // 65,536
  a.kvb    = a.logits + ROWS * R;         // 4,608
  a.P      = a.kvb + 4608;                // 2*512*4608 = 4,718,592 max
  _Float16* hp = (_Float16*)(a.P + 4718592);
  a.flow_h = hp;  hp += 262144;
  a.flow_l = hp;  hp += 262144;
  a.BKV_h  = hp;  hp += 4608 * 512;       // Wk | Wv | Wsh, [n][k]
  a.BKV_l  = hp;  hp += 4608 * 512;
  a.W1_h   = hp;  hp += 2097152;
  a.W1_l   = hp;  hp += 2097152;
  a.W2_h   = hp;  hp += 4194304;
  a.W2_l   = hp;  hp += 4194304;
  a.W3_h   = hp;  hp += 2097152;
  a.W3_l   = hp;  hp += 2097152;
  a.Wd_h   = hp;  hp += 65536;
  a.Wd_l   = hp;  hp += 65536;
  a.att_h  = hp;  hp += 262144;
  a.att_l  = hp;  hp += 262144;
  a.h1_h   = hp;  hp += 524288;
  a.h1_l   = hp;  hp += 524288;
  a.h2_h   = hp;  hp += 524288;
  a.h2_l   = hp;  hp += 524288;

  hipMemsetAsync(d_ws, 0, 128, stream);   // barrier counter + generation
  mega<<<NBLK, 256, 0, stream>>>(a);
}

// Round 11
// 417.773 us; speedup vs baseline: 12.1660x; 12.1660x over previous
//
#include <hip/hip_runtime.h>
#include <hip/hip_bf16.h>
#include <math.h>

// ---------------- problem dims (fixed by setup_inputs) ----------------
constexpr int B  = 8,  V = 64, E = 512, NS = 32;
constexpr int L  = 4,  H = 8,  D = 64,  M  = 1024, R = 128;
constexpr int HD = H * D;            // 512
constexpr int ROWS  = B * V;         // 512 distinct transformer rows
constexpr int SROWS = ROWS * NS;     // 16384 sample rows
constexpr int KVN = 4096;            // kv output columns (keys 2048 | vals 2048)

typedef _Float16 half8 __attribute__((ext_vector_type(8)));
typedef float floatx4 __attribute__((ext_vector_type(4)));

// ---------------- threefry2x32-20 (JAX-compatible, partitionable) ----------
struct TF2 { unsigned a, b; };
__host__ __device__ constexpr unsigned rotl32(unsigned x, int d) {
  return (x << d) | (x >> (32 - d));
}
__host__ __device__ constexpr TF2 threefry(unsigned k0, unsigned k1,
                                           unsigned x0, unsigned x1) {
  unsigned ks2 = k0 ^ k1 ^ 0x1BD11BDAu;
  x0 += k0; x1 += k1;
  const int ra[4] = {13, 15, 26, 6};
  const int rb[4] = {17, 29, 16, 24};
  for (int i = 0; i < 4; i++) { x0 += x1; x1 = rotl32(x1, ra[i]); x1 ^= x0; }
  x0 += k1;  x1 += ks2 + 1u;
  for (int i = 0; i < 4; i++) { x0 += x1; x1 = rotl32(x1, rb[i]); x1 ^= x0; }
  x0 += ks2; x1 += k0 + 2u;
  for (int i = 0; i < 4; i++) { x0 += x1; x1 = rotl32(x1, ra[i]); x1 ^= x0; }
  x0 += k0;  x1 += k1 + 3u;
  for (int i = 0; i < 4; i++) { x0 += x1; x1 = rotl32(x1, rb[i]); x1 ^= x0; }
  x0 += k1;  x1 += ks2 + 4u;
  for (int i = 0; i < 4; i++) { x0 += x1; x1 = rotl32(x1, ra[i]); x1 ^= x0; }
  x0 += ks2; x1 += k0 + 5u;
  return {x0, x1};
}
__device__ __forceinline__ unsigned tf_bits32(unsigned k0, unsigned k1,
                                              unsigned j) {
  TF2 r = threefry(k0, k1, 0u, j);
  return r.a ^ r.b;
}

__device__ __forceinline__ double waveReduceAdd64(double v) {
#pragma unroll
  for (int m = 32; m; m >>= 1) v += __shfl_xor(v, m, 64);
  return v;
}

__device__ __forceinline__ void split16(float v, _Float16& h, _Float16& l) {
  h = (_Float16)v;
  l = (_Float16)((v - (float)h) * 2048.0f);
}

// ---------------- merged prep: flow split + weight transpose/split +
//                  kv bias vector + logits zero, ONE launch -----------------
struct WArgs {
  const float* s[7];
  _Float16* h[7];
  _Float16* l[7];
};
// 0 Wsh(512,512) 1 Wk x32 2 Wv x32 3 W1 x4 4 W2 x4 5 W3 x4 6 Wd
__global__ __launch_bounds__(256) void prep_split(
    WArgs a, const float* __restrict__ flow, const float* __restrict__ bk,
    const float* __restrict__ bv, const float* __restrict__ bsh,
    _Float16* __restrict__ fh, _Float16* __restrict__ fl,
    float* __restrict__ kvb, float* __restrict__ logits) {
  __shared__ float tile[64][65];
  const int bid = blockIdx.x, t = threadIdx.x;
  if (bid < 275) {
    if (bid < 256) {
      const int base = (bid * 256 + t) * 4;
      float4 v = *(const float4*)&flow[base];
      float x[4] = {v.x, v.y, v.z, v.w};
#pragma unroll
      for (int j = 0; j < 4; j++) {
        _Float16 h, l;
        split16(x[j], h, l);
        fh[base + j] = h;
        fl[base + j] = l;
      }
    } else {
      const int idx = (bid - 256) * 256 + t;
      if (idx < KVN + HD) {
        float bb = (idx < 2048) ? bk[idx]
                 : (idx < 4096) ? bv[idx - 2048]
                                : bsh[idx - 4096];
        kvb[idx] = bb;
      }
    }
    return;
  }
  if (bid >= 2915) {  // zero logits
    const int idx = (bid - 2915) * 256 + t;
    float4 z = {0.f, 0.f, 0.f, 0.f};
    *(float4*)&logits[idx * 4] = z;
    return;
  }
  // weight transpose + split
  const int WS_OFF[8] = {0, 64, 320, 576, 1088, 2112, 2624, 2640};
  const int WS_K[7] = {512, 512, 512, 512, 1024, 1024, 512};
  const int WS_N[7] = {512, 64, 64, 1024, 1024, 512, 128};
  int wb = bid - 275;
  int mi = 0;
  while (wb >= WS_OFF[mi + 1]) mi++;
  int tt = wb - WS_OFF[mi];
  const int K = WS_K[mi], N = WS_N[mi];
  const int ktiles = K >> 6;
  const int per = ktiles * (N >> 6);
  const int z = tt / per;
  const int rem = tt - z * per;
  const int k0 = (rem % ktiles) * 64, n0 = (rem / ktiles) * 64;
  const size_t moff = (size_t)z * K * N;
  const float* src = a.s[mi] + moff;
  _Float16* dh = a.h[mi] + moff;
  _Float16* dl = a.l[mi] + moff;
#pragma unroll
  for (int i = 0; i < 16; i++) {
    int idx = i * 256 + t, r = idx >> 6, c = idx & 63;
    tile[r][c] = src[(size_t)(k0 + r) * N + n0 + c];
  }
  __syncthreads();
#pragma unroll
  for (int i = 0; i < 16; i++) {
    int idx = i * 256 + t, n = idx >> 6, k = idx & 63;
    float v = tile[k][n];
    _Float16 h, l;
    split16(v, h, l);
    dh[(size_t)(n0 + n) * K + k0 + k] = h;
    dl[(size_t)(n0 + n) * K + k0 + k] = l;
  }
}

// ---------------- 64x64 MFMA GEMM core macro-body (R9-verified) ------------
// Computes hh/mid 2x2 frags for tile (m0,n0), K-chunk [kbase, kbase+kchunk).
#define GEMM64_BODY(Ah, Al, Bh, Bl, K, m0, n0, kbase, kchunk, hh, mid, lds)  \
  {                                                                          \
    const int t = threadIdx.x, lane = t & 63, wave = t >> 6;                 \
    const int KT = (kchunk) >> 5;                                            \
    const int l15w = lane & 15, quadw = lane >> 4;                           \
    const _Float16* srcs[4] = {                                              \
        (Ah) + (size_t)(m0) * (K), (Al) + (size_t)(m0) * (K),                \
        (Bh) + (size_t)(n0) * (K), (Bl) + (size_t)(n0) * (K)};               \
    const _Float16* gsrc =                                                   \
        srcs[wave] + (size_t)l15w * (K) + quadw * 8 + (kbase);               \
    auto stage = [&](int buf, int kt) {                                      \
      _Float16* base = &lds[buf * 8192 + wave * 2048];                       \
      const int koff = kt * 32;                                              \
      _Pragma("unroll") for (int f = 0; f < 4; f++)                          \
          __builtin_amdgcn_global_load_lds(                                  \
              gsrc + (size_t)(f * 16) * (K) + koff, base + f * 512, 16, 0,   \
              0);                                                            \
    };                                                                       \
    const int wm = wave >> 1, wn = wave & 1;                                 \
    stage(0, 0);                                                             \
    __syncthreads();                                                         \
    for (int kt = 0; kt < KT; kt++) {                                        \
      if (kt + 1 < KT) stage((kt + 1) & 1, kt + 1);                          \
      const int bofs = (kt & 1) * 8192;                                      \
      half8 a_h[2], a_l[2], b_h[2], b_l[2];                                  \
      _Pragma("unroll") for (int i = 0; i < 2; i++) {                        \
        const int af = (wm * 2 + i) * 512 + lane * 8;                        \
        const int bf = (wn * 2 + i) * 512 + lane * 8;                        \
        a_h[i] = *(const half8*)&lds[bofs + af];                             \
        a_l[i] = *(const half8*)&lds[bofs + 2048 + af];                      \
        b_h[i] = *(const half8*)&lds[bofs + 4096 + bf];                      \
        b_l[i] = *(const half8*)&lds[bofs + 6144 + bf];                      \
      }                                                                      \
      _Pragma("unroll") for (int i = 0; i < 2; i++)                          \
          _Pragma("unroll") for (int j = 0; j < 2; j++) {                    \
        hh[i][j] = __builtin_amdgcn_mfma_f32_16x16x32_f16(a_h[i], b_h[j],    \
                                                          hh[i][j], 0, 0, 0);\
        mid[i][j] = __builtin_amdgcn_mfma_f32_16x16x32_f16(                  \
            a_h[i], b_l[j], mid[i][j], 0, 0, 0);                             \
        mid[i][j] = __builtin_amdgcn_mfma_f32_16x16x32_f16(                  \
            a_l[i], b_h[j], mid[i][j], 0, 0, 0);                             \
      }                                                                      \
      __syncthreads();                                                       \
    }                                                                        \
  }

#define GEMM_ACC_INIT(hh, mid)                                               \
  floatx4 hh[2][2], mid[2][2];                                               \
  _Pragma("unroll") for (int i = 0; i < 2; i++)                              \
      _Pragma("unroll") for (int j = 0; j < 2; j++) {                        \
    hh[i][j] = (floatx4){0.f, 0.f, 0.f, 0.f};                                \
    mid[i][j] = (floatx4){0.f, 0.f, 0.f, 0.f};                               \
  }

// ---------------- kv|shift GEMM: [512 x 4608 x 512], kz=1, direct ----------
__global__ __launch_bounds__(256) void gemm_kv(
    const _Float16* __restrict__ Ah, const _Float16* __restrict__ Al,
    const _Float16* __restrict__ Bh, const _Float16* __restrict__ Bl,
    const float* __restrict__ kvb, float* __restrict__ kv,
    float* __restrict__ att) {
  __shared__ __align__(16) _Float16 lds[2 * 8192];
  const int n0 = blockIdx.x * 64, m0 = blockIdx.y * 64;
  GEMM_ACC_INIT(hh, mid)
  GEMM64_BODY(Ah, Al, Bh, Bl, 512, m0, n0, 0, 512, hh, mid, lds)
  const int t = threadIdx.x, lane = t & 63, wave = t >> 6;
  const int wm = wave >> 1, wn = wave & 1, quad = lane >> 4, l15 = lane & 15;
#pragma unroll
  for (int i = 0; i < 2; i++)
#pragma unroll
    for (int j = 0; j < 2; j++)
#pragma unroll
      for (int r = 0; r < 4; r++) {
        float v = hh[i][j][r] + mid[i][j][r] * (1.0f / 2048.0f);
        const int m = m0 + (wm * 2 + i) * 16 + quad * 4 + r;
        const int n = n0 + (wn * 2 + j) * 16 + l15;
        v += kvb[n];
        if (n < KVN) kv[(size_t)m * KVN + n] = v;
        else att[(size_t)m * HD + (n - KVN)] = v;
      }
}

// ---------------- split-K GEMM to partial buffers (R9-identical) -----------
__global__ __launch_bounds__(256) void gemm_sp(
    const _Float16* __restrict__ Ah, const _Float16* __restrict__ Al,
    const _Float16* __restrict__ Bh, const _Float16* __restrict__ Bl,
    float* __restrict__ P, int K, int kchunk, int Ndim) {
  __shared__ __align__(16) _Float16 lds[2 * 8192];
  const int n0 = blockIdx.x * 64, m0 = blockIdx.y * 64;
  const int kbase = blockIdx.z * kchunk;
  GEMM_ACC_INIT(hh, mid)
  GEMM64_BODY(Ah, Al, Bh, Bl, K, m0, n0, kbase, kchunk, hh, mid, lds)
  const int t = threadIdx.x, lane = t & 63, wave = t >> 6;
  const int wm = wave >> 1, wn = wave & 1, quad = lane >> 4, l15 = lane & 15;
  float* Pz = P + (size_t)blockIdx.z * ROWS * Ndim;
#pragma unroll
  for (int i = 0; i < 2; i++)
#pragma unroll
    for (int j = 0; j < 2; j++)
#pragma unroll
      for (int r = 0; r < 4; r++) {
        float v = hh[i][j][r] + mid[i][j][r] * (1.0f / 2048.0f);
        const int m = m0 + (wm * 2 + i) * 16 + quad * 4 + r;
        const int n = n0 + (wn * 2 + j) * 16 + l15;
        Pz[(size_t)m * Ndim + n] = v;
      }
}

// ---------------- dist GEMM: kz=2 atomic into pre-zeroed logits ------------
// 2-addend f32 atomicAdd is commutative -> deterministic.
__global__ __launch_bounds__(256) void gemm_dist(
    const _Float16* __restrict__ Ah, const _Float16* __restrict__ Al,
    const _Float16* __restrict__ Bh, const _Float16* __restrict__ Bl,
    const float* __restrict__ bd, float* __restrict__ logits) {
  __shared__ __align__(16) _Float16 lds[2 * 8192];
  const int n0 = blockIdx.x * 64, m0 = blockIdx.y * 64;
  const int kbase = blockIdx.z * 256;
  GEMM_ACC_INIT(hh, mid)
  GEMM64_BODY(Ah, Al, Bh, Bl, 512, m0, n0, kbase, 256, hh, mid, lds)
  const int t = threadIdx.x, lane = t & 63, wave = t >> 6;
  const int wm = wave >> 1, wn = wave & 1, quad = lane >> 4, l15 = lane & 15;
#pragma unroll
  for (int i = 0; i < 2; i++)
#pragma unroll
    for (int j = 0; j < 2; j++)
#pragma unroll
      for (int r = 0; r < 4; r++) {
        float v = hh[i][j][r] + mid[i][j][r] * (1.0f / 2048.0f);
        const int m = m0 + (wm * 2 + i) * 16 + quad * 4 + r;
        const int n = n0 + (wn * 2 + j) * 16 + l15;
        if (blockIdx.z == 0) v += bd[n];
        atomicAdd(&logits[(size_t)m * R + n], v);
      }
}

// ---------------- epilogue: reduce kz + bias (+relu) -> fp16 h/l -----------
__global__ __launch_bounds__(256) void epi_h(
    const float* __restrict__ P, const float* __restrict__ bias,
    _Float16* __restrict__ Oh, _Float16* __restrict__ Ol, int Ndim, int kz,
    int relu) {
  const int n = blockIdx.x * 256 + threadIdx.x;
  const int m = blockIdx.y;
  const size_t MN = (size_t)ROWS * Ndim;
  const size_t id = (size_t)m * Ndim + n;
  float v = 0.0f;
  for (int z = 0; z < kz; z++) v += P[z * MN + id];
  v += bias[n];
  if (relu) v = fmaxf(v, 0.0f);
  _Float16 h, l;
  split16(v, h, l);
  Oh[id] = h;
  Ol[id] = l;
}

// ---------------- attention core (residual + LN1 fused), per row -----------
// q0/q1 = this thread's two att elements (from global or from registers).
__device__ __forceinline__ void attn_core(
    float* __restrict__ att, _Float16* __restrict__ att_h,
    _Float16* __restrict__ att_l, const float* __restrict__ kv,
    const float* __restrict__ g, const float* __restrict__ bb, int l, int row,
    float q0, float q1) {
  __shared__ float q[HD];
  __shared__ float sp[HD];
  __shared__ double rb[8];
  const int t = threadIdx.x;
  const int b_ = row >> 6;
  q[t] = q0;
  q[t + 256] = q1;
  __syncthreads();
#pragma unroll
  for (int rep = 0; rep < 2; rep++) {
    int idx = t + rep * 256;
    int h = idx >> 6, w = idx & 63;
    const float* kp = kv + (size_t)(b_ * 64 + w) * KVN + (l * 8 + h) * 64;
    const float* qp = q + h * D;
    double s = 0.0;
#pragma unroll 8
    for (int d = 0; d < 64; d++) s += (double)qp[d] * (double)kp[d];
    sp[idx] = (float)s * 0.125f;
  }
  __syncthreads();
  {
    int h = t >> 5, w0 = t & 31;
    float s0 = sp[h * 64 + w0], s1 = sp[h * 64 + w0 + 32];
    float mx = fmaxf(s0, s1);
#pragma unroll
    for (int m = 16; m; m >>= 1) mx = fmaxf(mx, __shfl_xor(mx, m, 32));
    float e0 = expf(s0 - mx), e1 = expf(s1 - mx);
    double sm = (double)e0 + (double)e1;
#pragma unroll
    for (int m = 16; m; m >>= 1) sm += __shfl_xor(sm, m, 32);
    sp[h * 64 + w0]      = (float)((double)e0 / sm);
    sp[h * 64 + w0 + 32] = (float)((double)e1 / sm);
  }
  __syncthreads();
  float x[2];
#pragma unroll
  for (int rep = 0; rep < 2; rep++) {
    int idx = t + rep * 256;
    int h = idx >> 6, d = idx & 63;
    const float* vp =
        kv + (size_t)(b_ * 64) * KVN + 2048 + (l * 8 + h) * 64 + d;
    const float* pp = sp + h * 64;
    double acc = 0.0;
#pragma unroll 8
    for (int w = 0; w < 64; w++)
      acc += (double)pp[w] * (double)vp[(size_t)w * KVN];
    x[rep] = q[idx] + (float)acc;
  }
  double s1 = (double)x[0] + (double)x[1];
  double s2 = (double)x[0] * (double)x[0] + (double)x[1] * (double)x[1];
  s1 = waveReduceAdd64(s1);
  s2 = waveReduceAdd64(s2);
  const int wid = t >> 6, lane = t & 63;
  if (lane == 0) { rb[wid] = s1; rb[4 + wid] = s2; }
  __syncthreads();
  double S1 = rb[0] + rb[1] + rb[2] + rb[3];
  double S2 = rb[4] + rb[5] + rb[6] + rb[7];
  double mean = S1 / (double)HD;
  double var  = S2 / (double)HD - mean * mean;
  double inv  = 1.0 / sqrt(var + (double)1e-5f);
  float y0 =
      (float)(((double)x[0] - mean) * inv * (double)g[t] + (double)bb[t]);
  float y1 = (float)(((double)x[1] - mean) * inv * (double)g[t + 256] +
                     (double)bb[t + 256]);
  att[row * HD + t] = y0;
  att[row * HD + 256 + t] = y1;
  _Float16 h0, l0, h1v, l1v;
  split16(y0, h0, l0);
  split16(y1, h1v, l1v);
  att_h[row * HD + t] = h0;
  att_l[row * HD + t] = l0;
  att_h[row * HD + 256 + t] = h1v;
  att_l[row * HD + 256 + t] = l1v;
}

// ---------------- standalone attention (layer 0) ---------------------------
__global__ __launch_bounds__(256) void attn_kernel(
    float* __restrict__ att, _Float16* __restrict__ att_h,
    _Float16* __restrict__ att_l, const float* __restrict__ kv,
    const float* __restrict__ g, const float* __restrict__ bb, int l) {
  const int t = threadIdx.x, row = blockIdx.x;
  float q0 = att[row * HD + t];
  float q1 = att[row * HD + 256 + t];
  attn_core(att, att_h, att_l, kv, g, bb, l, row, q0, q1);
}

// ---------------- W3-epilogue + residual + LN2 (+ fused next attn) ---------
__global__ __launch_bounds__(256) void epi_ln_attn(
    float* __restrict__ att, _Float16* __restrict__ att_h,
    _Float16* __restrict__ att_l, const float* __restrict__ P,
    const float* __restrict__ b3, const float* __restrict__ g2,
    const float* __restrict__ bb2, const float* __restrict__ kv,
    const float* __restrict__ g1, const float* __restrict__ bb1, int next_l) {
  __shared__ double rb[8];
  const int t = threadIdx.x, row = blockIdx.x;
  const size_t MN = (size_t)ROWS * HD;
  const size_t id0 = (size_t)row * HD + t;
  float h0 = 0.0f, h1s = 0.0f;
  for (int z = 0; z < 8; z++) {
    h0 += P[z * MN + id0];
    h1s += P[z * MN + id0 + 256];
  }
  h0 += b3[t];
  h1s += b3[t + 256];
  float x0 = att[id0] + h0;
  float x1 = att[id0 + 256] + h1s;
  double s1 = (double)x0 + (double)x1;
  double s2 = (double)x0 * (double)x0 + (double)x1 * (double)x1;
  s1 = waveReduceAdd64(s1);
  s2 = waveReduceAdd64(s2);
  const int wid = t >> 6, lane = t & 63;
  if (lane == 0) { rb[wid] = s1; rb[4 + wid] = s2; }
  __syncthreads();
  double S1 = rb[0] + rb[1] + rb[2] + rb[3];
  double S2 = rb[4] + rb[5] + rb[6] + rb[7];
  double mean = S1 / (double)HD;
  double var  = S2 / (double)HD - mean * mean;
  double inv  = 1.0 / sqrt(var + (double)1e-5f);
  float y0 =
      (float)(((double)x0 - mean) * inv * (double)g2[t] + (double)bb2[t]);
  float y1 = (float)(((double)x1 - mean) * inv * (double)g2[t + 256] +
                     (double)bb2[t + 256]);
  if (next_l < 0) {
    att[id0] = y0;
    att[id0 + 256] = y1;
    _Float16 hh0, ll0, hh1, ll1;
    split16(y0, hh0, ll0);
    split16(y1, hh1, ll1);
    att_h[id0] = hh0;
    att_l[id0] = ll0;
    att_h[id0 + 256] = hh1;
    att_l[id0 + 256] = ll1;
  } else {
    __syncthreads();  // rb done before attn_core reuses its own LDS
    attn_core(att, att_h, att_l, kv, g1, bb1, next_l, row, y0, y1);
  }
}

// ---------------- gumbel-argmax sampling (bit-exact vs JAX; verified) ------
__global__ __launch_bounds__(256) void sample_kernel(
    const float* __restrict__ logits, float* __restrict__ out) {
  constexpr TF2 KC = threefry(0u, 1u, 0u, 0u);  // fold_in(key(1), 0)
  constexpr TF2 KU = threefry(0u, 1u, 0u, 1u);  // fold_in(key(1), 1)
  const int lane = threadIdx.x & 63;
  const int wid = threadIdx.x >> 6;
  const int row = blockIdx.x * 4 + wid;
  const float* lrow = logits + (row >> 5) * R;
  float bvv = -1e30f;
  int bi = 0;
#pragma unroll
  for (int rep = 0; rep < 2; rep++) {
    int r = lane + rep * 64;
    unsigned j = (unsigned)row * (unsigned)R + (unsigned)r;
    unsigned bits = tf_bits32(KC.a, KC.b, j);
    float f = __uint_as_float((bits >> 9) | 0x3f800000u) - 1.0f;
    float u = fmaxf(f, 1.17549435e-38f);
    float gv = -logf(-logf(u));
    float v = lrow[r] + gv;
    if (v > bvv) { bvv = v; bi = r; }
  }
#pragma unroll
  for (int m = 32; m; m >>= 1) {
    float ov = __shfl_xor(bvv, m, 64);
    int oi = __shfl_xor(bi, m, 64);
    if (ov > bvv || (ov == bvv && oi < bi)) { bvv = ov; bi = oi; }
  }
  if (lane == 0) {
    unsigned ub = tf_bits32(KU.a, KU.b, (unsigned)row);
    float u = __uint_as_float((ub >> 9) | 0x3f800000u) - 1.0f;
    out[row] = ((float)bi + u) * (1.0f / 128.0f);
  }
}

// ---------------- launcher ----------------
extern "C" void kernel_launch(void* const* d_in, const int* in_sizes, int n_in,
                              void* d_out, int out_size, void* d_ws,
                              size_t ws_size, hipStream_t stream) {
  (void)in_sizes; (void)n_in; (void)out_size; (void)ws_size;
  const float* flow = (const float*)d_in[0];
  const float* Wsh  = (const float*)d_in[1];
  const float* bsh  = (const float*)d_in[2];
  const float* Wk   = (const float*)d_in[3];
  const float* bk   = (const float*)d_in[4];
  const float* Wv   = (const float*)d_in[5];
  const float* bv   = (const float*)d_in[6];
  const float* ln1g = (const float*)d_in[7];
  const float* ln1b = (const float*)d_in[8];
  const float* W1   = (const float*)d_in[9];
  const float* b1   = (const float*)d_in[10];
  const float* W2   = (const float*)d_in[11];
  const float* b2   = (const float*)d_in[12];
  const float* W3   = (const float*)d_in[13];
  const float* b3   = (const float*)d_in[14];
  const float* ln2g = (const float*)d_in[15];
  const float* ln2b = (const float*)d_in[16];
  const float* Wd   = (const float*)d_in[17];
  const float* bd   = (const float*)d_in[18];

  // ---- workspace carve-up (f32 region, partial buf, fp16 region) ----------
  float* ws = (float*)d_ws;
  float* kv     = ws;                         // 512*4096 f32
  float* att    = kv + ROWS * KVN;            // 262,144
  float* logits = att + ROWS * HD;            // 65,536 (zeroed in prep)
  float* kvb    = logits + ROWS * R;          // 4,608
  float* P      = kvb + 4608;                 // up to 8*512*1024 = 4,194,304
  _Float16* hp = (_Float16*)(P + 4718592);
  _Float16* flow_h = hp;            hp += 262144;
  _Float16* flow_l = hp;            hp += 262144;
  _Float16* BKV_h  = hp;            hp += 4608 * 512;  // Wk | Wv | Wsh, [n][k]
  _Float16* BKV_l  = hp;            hp += 4608 * 512;
  _Float16* W1_h   = hp;            hp += 2097152;
  _Float16* W1_l   = hp;            hp += 2097152;
  _Float16* W2_h   = hp;            hp += 4194304;
  _Float16* W2_l   = hp;            hp += 4194304;
  _Float16* W3_h   = hp;            hp += 2097152;
  _Float16* W3_l   = hp;            hp += 2097152;
  _Float16* Wd_h   = hp;            hp += 65536;
  _Float16* Wd_l   = hp;            hp += 65536;
  _Float16* att_h  = hp;            hp += 262144;
  _Float16* att_l  = hp;            hp += 262144;
  _Float16* h1_h   = hp;            hp += 524288;
  _Float16* h1_l   = hp;            hp += 524288;
  _Float16* h2_h   = hp;            hp += 524288;
  _Float16* h2_l   = hp;            hp += 524288;

  // ---- P0: merged prep + weight transpose/split + logits zero -------------
  WArgs wa;
  wa.s[0] = Wsh; wa.h[0] = BKV_h + 4096 * 512; wa.l[0] = BKV_l + 4096 * 512;
  wa.s[1] = Wk;  wa.h[1] = BKV_h;              wa.l[1] = BKV_l;
  wa.s[2] = Wv;  wa.h[2] = BKV_h + 2048 * 512; wa.l[2] = BKV_l + 2048 * 512;
  wa.s[3] = W1;  wa.h[3] = W1_h;  wa.l[3] = W1_l;
  wa.s[4] = W2;  wa.h[4] = W2_h;  wa.l[4] = W2_l;
  wa.s[5] = W3;  wa.h[5] = W3_h;  wa.l[5] = W3_l;
  wa.s[6] = Wd;  wa.h[6] = Wd_h;  wa.l[6] = Wd_l;
  prep_split<<<2979, 256, 0, stream>>>(wa, flow, bk, bv, bsh, flow_h, flow_l,
                                       kvb, logits);

  // ---- fused keys|vals|shift GEMM: kz=1, direct epilogue ------------------
  gemm_kv<<<dim3(72, 8), 256, 0, stream>>>(flow_h, flow_l, BKV_h, BKV_l, kvb,
                                           kv, att);
  // ---- layer 0 attention ----
  attn_kernel<<<ROWS, 256, 0, stream>>>(att, att_h, att_l, kv, ln1g, ln1b, 0);

  // ---- transformer layers (attn l+1 fused into epi_ln of layer l) ---------
  for (int l = 0; l < L; l++) {
    gemm_sp<<<dim3(16, 8, 4), 256, 0, stream>>>(
        att_h, att_l, W1_h + (size_t)l * 524288, W1_l + (size_t)l * 524288, P,
        512, 128, M);
    epi_h<<<dim3(4, ROWS), 256, 0, stream>>>(P, b1 + l * M, h1_h, h1_l, M, 4,
                                             1);
    gemm_sp<<<dim3(16, 8, 8), 256, 0, stream>>>(
        h1_h, h1_l, W2_h + (size_t)l * 1048576, W2_l + (size_t)l * 1048576, P,
        1024, 128, M);
    epi_h<<<dim3(4, ROWS), 256, 0, stream>>>(P, b2 + l * M, h2_h, h2_l, M, 8,
                                             1);
    gemm_sp<<<dim3(8, 8, 8), 256, 0, stream>>>(
        h2_h, h2_l, W3_h + (size_t)l * 524288, W3_l + (size_t)l * 524288, P,
        1024, 128, HD);
    const int nl = (l + 1 < L) ? (l + 1) : -1;
    epi_ln_attn<<<ROWS, 256, 0, stream>>>(
        att, att_h, att_l, P, b3 + l * HD, ln2g + l * HD, ln2b + l * HD, kv,
        ln1g + (nl < 0 ? 0 : nl) * HD, ln1b + (nl < 0 ? 0 : nl) * HD, nl);
  }
  // ---- distribution head (kz=2 deterministic atomic) + sampling -----------
  gemm_dist<<<dim3(2, 8, 2), 256, 0, stream>>>(att_h, att_l, Wd_h, Wd_l, bd,
                                               logits);
  sample_kernel<<<SROWS / 4, 256, 0, stream>>>(logits, (float*)d_out);
}